// Round 1
// baseline (144.561 us; speedup 1.0000x reference)
//
#include <hip/hip_runtime.h>
#include <hip/hip_bf16.h>

// Problem: AdditiveMul  (N_Q=2048, N_K=2048, N_HEAD=8, D_HEAD=64)
// out[i,j,h] = softmax_h( relu( dot(q[i,h,:], attn[0,h,0:64]) + dot(k[j,h,:], attn[0,h,64:128]) ) )
// Output: (2048, 2048, 8) f32 = 134 MB  ->  store-bandwidth bound (~21 us floor at 6.3 TB/s).

#define N_Q   2048
#define N_K   2048
#define N_HEAD 8
#define D_HEAD 64

// ---------------------------------------------------------------------------
// Kernel 1: sq[i,h] = sum_d q[i,h,d]*attn[h,d];  sk[j,h] = sum_d k[j,h,d]*attn[h,64+d]
// 8 lanes per (row,head) pair; each lane reads 8 floats (two float4) -> wave
// covers 2 KB contiguous.  Shuffle-reduce over the 8 lanes.
// ---------------------------------------------------------------------------
__global__ __launch_bounds__(256) void proj_kernel(
    const float* __restrict__ q, const float* __restrict__ k,
    const float* __restrict__ attn,
    float* __restrict__ sq, float* __restrict__ sk)
{
    int tid = blockIdx.x * blockDim.x + threadIdx.x;
    int lane8 = tid & 7;          // position within the 8-lane group
    int pair  = tid >> 3;         // global pair id: [0, 2*N_Q*N_HEAD)
    const int PAIRS = N_Q * N_HEAD;
    bool is_k = pair >= PAIRS;
    int p = is_k ? (pair - PAIRS) : pair;   // p = row*8 + h
    int h = p & (N_HEAD - 1);

    const float* src = is_k ? k : q;
    const float* a   = attn + h * (2 * D_HEAD) + (is_k ? D_HEAD : 0);

    const float4* s4 = (const float4*)(src + (size_t)p * D_HEAD + lane8 * 8);
    const float4* a4 = (const float4*)(a + lane8 * 8);
    float4 x0 = s4[0], x1 = s4[1];
    float4 w0 = a4[0], w1 = a4[1];
    float sum = x0.x*w0.x + x0.y*w0.y + x0.z*w0.z + x0.w*w0.w
              + x1.x*w1.x + x1.y*w1.y + x1.z*w1.z + x1.w*w1.w;

    // reduce across the 8 lanes of this group (they are contiguous in the wave)
    sum += __shfl_xor(sum, 1);
    sum += __shfl_xor(sum, 2);
    sum += __shfl_xor(sum, 4);

    if (lane8 == 0) {
        (is_k ? sk : sq)[p] = sum;
    }
}

// ---------------------------------------------------------------------------
// Kernel 2: per (i,j) thread: v[h] = relu(sq[i,h]+sk[j,h]); softmax over h=0..7;
// write 8 contiguous floats (two float4 stores -> 32 B/lane, fully coalesced).
// ---------------------------------------------------------------------------
__global__ __launch_bounds__(256) void softmax_kernel(
    const float* __restrict__ sq, const float* __restrict__ sk,
    float* __restrict__ out)
{
    int j = blockIdx.x * blockDim.x + threadIdx.x;  // 0..N_K-1
    int i = blockIdx.y;                             // 0..N_Q-1

    // sq[i,:] : same address for every thread in the block -> broadcast from L1
    float4 q0 = *(const float4*)(sq + i * N_HEAD);
    float4 q1 = *(const float4*)(sq + i * N_HEAD + 4);
    // sk[j,:] : consecutive threads read consecutive 32 B -> coalesced
    float4 k0 = *(const float4*)(sk + j * N_HEAD);
    float4 k1 = *(const float4*)(sk + j * N_HEAD + 4);

    float v[8];
    v[0] = q0.x + k0.x; v[1] = q0.y + k0.y; v[2] = q0.z + k0.z; v[3] = q0.w + k0.w;
    v[4] = q1.x + k1.x; v[5] = q1.y + k1.y; v[6] = q1.z + k1.z; v[7] = q1.w + k1.w;

    float m = 0.0f;  // relu output >= 0, so max >= 0
    #pragma unroll
    for (int h = 0; h < 8; ++h) {
        v[h] = fmaxf(v[h], 0.0f);
        m = fmaxf(m, v[h]);
    }
    float s = 0.0f;
    #pragma unroll
    for (int h = 0; h < 8; ++h) {
        v[h] = __expf(v[h] - m);
        s += v[h];
    }
    float inv = 1.0f / s;

    float4 o0 = make_float4(v[0]*inv, v[1]*inv, v[2]*inv, v[3]*inv);
    float4 o1 = make_float4(v[4]*inv, v[5]*inv, v[6]*inv, v[7]*inv);

    float* dst = out + ((size_t)i * N_K + j) * N_HEAD;
    *(float4*)(dst)     = o0;
    *(float4*)(dst + 4) = o1;
}

extern "C" void kernel_launch(void* const* d_in, const int* in_sizes, int n_in,
                              void* d_out, int out_size, void* d_ws, size_t ws_size,
                              hipStream_t stream) {
    const float* q    = (const float*)d_in[0];
    const float* k    = (const float*)d_in[1];
    const float* attn = (const float*)d_in[2];
    float* out = (float*)d_out;

    float* sq = (float*)d_ws;                    // N_Q*N_HEAD floats
    float* sk = sq + N_Q * N_HEAD;               // N_K*N_HEAD floats

    // Kernel 1: 2 * N_Q * N_HEAD pairs, 8 threads each
    int total_threads = 2 * N_Q * N_HEAD * 8;    // 262144
    proj_kernel<<<dim3(total_threads / 256), dim3(256), 0, stream>>>(q, k, attn, sq, sk);

    // Kernel 2: one thread per (i,j)
    softmax_kernel<<<dim3(N_K / 256, N_Q), dim3(256), 0, stream>>>(sq, sk, out);
}